// Round 25
// baseline (75.504 us; speedup 1.0000x reference)
//
#include <hip/hip_runtime.h>

// Problem constants
#define NQ 20
#define DIMQ (1 << NQ)          // 2^20
#define NB 16                   // BATCH
#define NT 4                    // N_TERMS
#define RBITS 15                // low bits untouched by gates
#define NCOL (1 << (RBITS + 4)) // 2^15 r-values * 16 batches = 524288 columns
#define TILES 4                 // column-tiles per block (double-buffered)
#define NBLK (NCOL / 64 / TILES) // 2048 blocks

// U table layout in ws/LDS: per (k,b): 36 floats (16 complex interleaved + 4 pad)
//   base = (k*16 + b) * 36 ; entry (i,j): re at base + (i*4+j)*2, im at +1
#define USTRIDE 36
#define UTOT (64 * USTRIDE)     // 2304 floats = 9216 B

// Complex MAC via packed-FP32 VOP3P: o += u * s  (u=(ur,ui), s=(sr,si)).
__device__ __forceinline__ void cfma(float2& o, const float2 u, const float2 s) {
  asm("v_pk_fma_f32 %0, %1, %2, %0 op_sel_hi:[0,1,1]\n\t"
      "v_pk_fma_f32 %0, %1, %2, %0 op_sel:[1,1,0] op_sel_hi:[1,0,1] neg_lo:[1,0,0]"
      : "+v"(o) : "v"(u), "v"(s));
}
// o = u * s (no accumulate); early-clobber since %0 is written before last read.
__device__ __forceinline__ float2 cmul(const float2 u, const float2 s) {
  float2 o;
  asm("v_pk_mul_f32 %0, %1, %2 op_sel_hi:[0,1]\n\t"
      "v_pk_fma_f32 %0, %1, %2, %0 op_sel:[1,1,0] op_sel_hi:[1,0,1] neg_lo:[1,0,0]"
      : "=&v"(o) : "v"(u), "v"(s));
  return o;
}

// ---------------------------------------------------------------------------
// Kernel A: U[k,b] = exp(-i * H_k * t_{k,b}),  H_k = 0.5*(A + A^H), A = Hr + i Hi
// 256 threads: 64 tasks (k,b) x 4 rows. Scaling (2^-4) + 8-term Taylor +
// 4 squarings (trunc error ~1e-10, invisible at fp32 / 2.1e-4 threshold).
// ---------------------------------------------------------------------------
__global__ __launch_bounds__(256) void compute_u_kernel(
    const float* __restrict__ Hre, const float* __restrict__ Him,
    const float* __restrict__ tevo, float* __restrict__ uout) {
  __shared__ float er_s[64][4][4];
  __shared__ float ei_s[64][4][4];

  const int tid  = threadIdx.x;   // 0..255
  const int task = tid >> 2;      // 0..63
  const int row  = tid & 3;       // 0..3
  const int k    = task >> 4;     // 0..3
  const int b    = task & 15;     // 0..15

  float Ar[4][4], Ai[4][4];
#pragma unroll
  for (int i = 0; i < 4; i++) {
#pragma unroll
    for (int j = 0; j < 4; j++) {
      Ar[i][j] = Hre[k * 16 + i * 4 + j];
      Ai[i][j] = Him[k * 16 + i * 4 + j];
    }
  }
  const float t = tevo[k * NB + b];
  const float ts = t * (1.0f / 16.0f);  // scale 2^-4 folded in

  // G = -i * H * ts ; H = 0.5*(A + A^H)
  float Gr[4][4], Gi[4][4];
#pragma unroll
  for (int i = 0; i < 4; i++) {
#pragma unroll
    for (int j = 0; j < 4; j++) {
      const float hr = 0.5f * (Ar[i][j] + Ar[j][i]);
      const float hi = 0.5f * (Ai[i][j] - Ai[j][i]);
      Gr[i][j] = ts * hi;
      Gi[i][j] = -ts * hr;
    }
  }

  // Taylor: E = I + sum_{m=1..8} G^m/m!   (row `row` only; full G in regs)
  float Er[4], Ei[4], Tr[4], Ti[4];
#pragma unroll
  for (int j = 0; j < 4; j++) {
    Er[j] = (j == row) ? 1.0f : 0.0f;
    Ei[j] = 0.0f;
    Tr[j] = Er[j];
    Ti[j] = 0.0f;
  }
#pragma unroll
  for (int m = 1; m <= 8; m++) {
    const float inv = 1.0f / (float)m;
    float nr[4], ni[4];
#pragma unroll
    for (int j = 0; j < 4; j++) {
      float ar = 0.0f, ai = 0.0f;
#pragma unroll
      for (int p = 0; p < 4; p++) {
        ar += Tr[p] * Gr[p][j] - Ti[p] * Gi[p][j];
        ai += Tr[p] * Gi[p][j] + Ti[p] * Gr[p][j];
      }
      nr[j] = ar * inv;
      ni[j] = ai * inv;
    }
#pragma unroll
    for (int j = 0; j < 4; j++) {
      Tr[j] = nr[j]; Ti[j] = ni[j];
      Er[j] += nr[j]; Ei[j] += ni[j];
    }
  }

  // 4 squarings via LDS (uniform trip count -> barriers are safe)
  for (int q = 0; q < 4; q++) {
    __syncthreads();
#pragma unroll
    for (int j = 0; j < 4; j++) {
      er_s[task][row][j] = Er[j];
      ei_s[task][row][j] = Ei[j];
    }
    __syncthreads();
    float nr[4], ni[4];
#pragma unroll
    for (int j = 0; j < 4; j++) {
      float ar = 0.0f, ai = 0.0f;
#pragma unroll
      for (int p = 0; p < 4; p++) {
        ar += Er[p] * er_s[task][p][j] - Ei[p] * ei_s[task][p][j];
        ai += Er[p] * ei_s[task][p][j] + Ei[p] * er_s[task][p][j];
      }
      nr[j] = ar; ni[j] = ai;
    }
#pragma unroll
    for (int j = 0; j < 4; j++) { Er[j] = nr[j]; Ei[j] = ni[j]; }
  }

  // Store U rows: layout [k][b][16 complex interleaved], row stride 36 floats
  const int ubase = (k * 16 + b) * USTRIDE;
#pragma unroll
  for (int j = 0; j < 4; j++) {
    uout[ubase + (row * 4 + j) * 2]     = Er[j];
    uout[ubase + (row * 4 + j) * 2 + 1] = Ei[j];
  }
}

// ---------------------------------------------------------------------------
// DMA one 64-col tile (16 KiB, [g][re64|im64]) into dst_base: 4 instrs/wave.
// instr p: sub = l>>4; g = 2p + (sub>>1); sub&1 ? im : re; cols (l&15)*4..+3.
// ---------------------------------------------------------------------------
__device__ __forceinline__ void dma_tile(const float* __restrict__ sre,
                                         const float* __restrict__ sim,
                                         int c0, float* dst_base, int w, int l) {
#pragma unroll
  for (int t = 0; t < 4; t++) {
    const int p   = w * 4 + t;            // 0..15, wave-uniform
    const int sub = l >> 4;               // 0..3
    const int g   = 2 * p + (sub >> 1);   // 0..31
    const float* base = (sub & 1) ? sim : sre;
    const float* src  = base + (g << 19) + c0 + (l & 15) * 4;
    float* dst = dst_base + p * 256;      // wave-uniform base, lane*16B implicit
    __builtin_amdgcn_global_load_lds(
        (const __attribute__((address_space(1))) float*)(const void*)src,
        (__attribute__((address_space(3))) float*)(void*)dst, 16, 0, 0);
  }
}

// ---------------------------------------------------------------------------
// Compute + store one tile from an LDS state buffer (r22 body verbatim).
// ---------------------------------------------------------------------------
__device__ __forceinline__ void compute_tile(const float* __restrict__ st,
                                             const float* __restrict__ ul,
                                             int c0, int w, int l, int b, int q0,
                                             float* __restrict__ out) {
  // own quadrant into registers: 8 paired reads (ds_read2_b32)
  float2 s[8];
#pragma unroll
  for (int m = 0; m < 8; m++) {
    const int a = (w * 8 + m) * 128 + l;
    s[m].x = st[a];
    s[m].y = st[a + 64];
  }

  float2 o[8];

  // ---- k = 3 (g bits [1:0]) : in-thread; initializes acc ----
  {
    const float* ub = &ul[(3 * 16 + b) * USTRIDE];
#pragma unroll
    for (int i = 0; i < 4; i++) {
      const float4 v0 = *(const float4*)(ub + i * 8);
      const float4 v1 = *(const float4*)(ub + i * 8 + 4);
      const float2 u0 = make_float2(v0.x, v0.y), u1 = make_float2(v0.z, v0.w);
      const float2 u2 = make_float2(v1.x, v1.y), u3 = make_float2(v1.z, v1.w);
#pragma unroll
      for (int h = 0; h < 2; h++) {
        const int om = h * 4 + i;
        o[om] = cmul(u0, s[h * 4 + 0]);
        cfma(o[om], u1, s[h * 4 + 1]);
        cfma(o[om], u2, s[h * 4 + 2]);
        cfma(o[om], u3, s[h * 4 + 3]);
      }
    }
  }

  // ---- k = 2 (g bits [2:1]) : in-thread ----
  {
    const float* ub = &ul[(2 * 16 + b) * USTRIDE];
#pragma unroll
    for (int i = 0; i < 4; i++) {
      const float4 v0 = *(const float4*)(ub + i * 8);
      const float4 v1 = *(const float4*)(ub + i * 8 + 4);
      const float2 u0 = make_float2(v0.x, v0.y), u1 = make_float2(v0.z, v0.w);
      const float2 u2 = make_float2(v1.x, v1.y), u3 = make_float2(v1.z, v1.w);
#pragma unroll
      for (int l0 = 0; l0 < 2; l0++) {
        const int om = i * 2 + l0;
        cfma(o[om], u0, s[l0]);
        cfma(o[om], u1, s[2 + l0]);
        cfma(o[om], u2, s[4 + l0]);
        cfma(o[om], u3, s[6 + l0]);
      }
    }
  }

  // ---- k = 1 (g bits [3:2]) + k = 0's j=w^1 term (reuses p[]) ----
  {
    float2 p[8];
    const int pq = w ^ 1;
#pragma unroll
    for (int m = 0; m < 8; m++) {
      const int a = (pq * 8 + m) * 128 + l;
      p[m].x = st[a];
      p[m].y = st[a + 64];
    }
    const float* ub1 = &ul[(1 * 16 + b) * USTRIDE];
#pragma unroll
    for (int mh = 0; mh < 2; mh++) {
      const int i = q0 * 2 + mh;
      const float* row = ub1 + i * 8;
#pragma unroll
      for (int j2 = 0; j2 < 2; j2++) {
        const float2 uo = *(const float2*)(row + (q0 * 2 + j2) * 2);
        const float2 up = *(const float2*)(row + ((q0 ^ 1) * 2 + j2) * 2);
#pragma unroll
        for (int ml = 0; ml < 4; ml++) {
          const int om = mh * 4 + ml;
          cfma(o[om], uo, s[j2 * 4 + ml]);
          cfma(o[om], up, p[j2 * 4 + ml]);
        }
      }
    }
    const float* ub0 = &ul[b * USTRIDE];
    const float2 u01 = *(const float2*)(ub0 + (w * 4 + (w ^ 1)) * 2);
#pragma unroll
    for (int m = 0; m < 8; m++) cfma(o[m], u01, p[m]);
  }

  // ---- k = 0 remaining: j = w (own regs), j = w^2, w^3 (paired LDS) ----
  {
    const float* ub0 = &ul[b * USTRIDE];
    const float2 u00 = *(const float2*)(ub0 + (w * 4 + w) * 2);
#pragma unroll
    for (int m = 0; m < 8; m++) cfma(o[m], u00, s[m]);
#pragma unroll
    for (int d = 2; d < 4; d++) {
      const int jq = w ^ d;
      const float2 uj = *(const float2*)(ub0 + (w * 4 + jq) * 2);
#pragma unroll
      for (int m = 0; m < 8; m++) {
        const int a = (jq * 8 + m) * 128 + l;
        float2 t;
        t.x = st[a];
        t.y = st[a + 64];
        cfma(o[m], uj, t);
      }
    }
  }

  // stores: 64 lanes x 4B contiguous = 256B (full lines) per instruction
#pragma unroll
  for (int m = 0; m < 8; m++) {
    const int off = c0 + l + ((w * 8 + m) << 19);
    __builtin_nontemporal_store(o[m].x, out + off);               // real
    __builtin_nontemporal_store(o[m].y, out + off + (1 << 24));   // imag
  }
}

// ---------------------------------------------------------------------------
// Kernel B (r22 compute core + double-buffered DMA pipeline, T3/T4 style):
// Block processes TILES=4 consecutive 64-col tiles. While computing tile t
// from st[t&1], tile t+1's DMA streams into st[(t+1)&1]. Iteration end:
//   s_waitcnt vmcnt(16)  -- retires the 4 DMA ops (older than the 16 NT
//                           stores just issued) WITHOUT draining the stores
//   s_barrier            -- raw barrier (no implicit vmcnt(0) drain)
// so HBM load latency hides entirely under compute. WAR on the buffer being
// re-DMA'd is protected by the previous iteration's barrier (all reads of
// that buffer retired before any wave crossed it).
// LDS = 9216 U + 2x16384 state = 41984 B -> 3 blocks/CU; the bet: pipelined
// operands keep the LDS pipe saturated at 12 waves/CU, beating r22's
// 24-wave latency-hiding-by-occupancy.
// ---------------------------------------------------------------------------
__global__ __launch_bounds__(256, 4) void apply_gates_kernel(
    const float* __restrict__ sre, const float* __restrict__ sim,
    const float* __restrict__ u, float* __restrict__ out) {
  __shared__ __align__(16) float ul[UTOT];          // 9216 B U table
  __shared__ __align__(16) float st[2][32 * 128];   // 2 x 16 KiB state buffers
  const int tid = threadIdx.x;
  const int w   = tid >> 6;     // wave = owned quadrant (g bits [4:3])
  const int l   = tid & 63;     // lane = column within tile
  const int b   = l & 15;
  const int q0  = w & 1;        // g bit 3
  const int tbase = blockIdx.x * TILES;

  // prologue: DMA tile 0 into buffer 0; stage U; full drain once
  dma_tile(sre, sim, tbase * 64, st[0], w, l);
#pragma unroll
  for (int q = 0; q < 9; q++) ul[tid + q * 256] = u[tid + q * 256];
  __syncthreads();   // vmcnt(0) + lgkmcnt(0): tile 0 and U ready

#pragma unroll
  for (int t = 0; t < TILES; t++) {
    if (t + 1 < TILES)
      dma_tile(sre, sim, (tbase + t + 1) * 64, st[(t + 1) & 1], w, l);

    compute_tile(st[t & 1], ul, (tbase + t) * 64, w, l, b, q0, out);

    if (t + 1 < TILES) {
      // retire the 4 DMA ops (older than this tile's 16 stores) -- never 0
      asm volatile("s_waitcnt vmcnt(16)" ::: "memory");
      __builtin_amdgcn_s_barrier();
    }
  }
}

extern "C" void kernel_launch(void* const* d_in, const int* in_sizes, int n_in,
                              void* d_out, int out_size, void* d_ws, size_t ws_size,
                              hipStream_t stream) {
  const float* Hre  = (const float*)d_in[0];
  const float* Him  = (const float*)d_in[1];
  const float* tevo = (const float*)d_in[2];
  const float* sre  = (const float*)d_in[3];
  const float* sim  = (const float*)d_in[4];
  float* out = (float*)d_out;
  float* uws = (float*)d_ws;  // UTOT floats = 9216 B

  compute_u_kernel<<<1, 256, 0, stream>>>(Hre, Him, tevo, uws);
  apply_gates_kernel<<<NBLK, 256, 0, stream>>>(sre, sim, uws, out);
}

// Round 26
// 50.453 us; speedup vs baseline: 1.4965x; 1.4965x over previous
//
#include <hip/hip_runtime.h>

// Problem constants
#define NQ 20
#define DIMQ (1 << NQ)          // 2^20
#define NB 16                   // BATCH
#define NT 4                    // N_TERMS
#define RBITS 15                // low bits untouched by gates
#define NCOL (1 << (RBITS + 4)) // 2^15 r-values * 16 batches = 524288 columns

// U table layout in ws/LDS: per (k,b): 36 floats (16 complex interleaved + 4 pad)
//   base = (k*16 + b) * 36 ; entry (i,j): re at base + (i*4+j)*2, im at +1
#define USTRIDE 36
#define UTOT (64 * USTRIDE)     // 2304 floats = 9216 B

// Complex MAC via packed-FP32 VOP3P: o += u * s  (u=(ur,ui), s=(sr,si)).
__device__ __forceinline__ void cfma(float2& o, const float2 u, const float2 s) {
  asm("v_pk_fma_f32 %0, %1, %2, %0 op_sel_hi:[0,1,1]\n\t"
      "v_pk_fma_f32 %0, %1, %2, %0 op_sel:[1,1,0] op_sel_hi:[1,0,1] neg_lo:[1,0,0]"
      : "+v"(o) : "v"(u), "v"(s));
}
// o = u * s (no accumulate); early-clobber since %0 is written before last read.
__device__ __forceinline__ float2 cmul(const float2 u, const float2 s) {
  float2 o;
  asm("v_pk_mul_f32 %0, %1, %2 op_sel_hi:[0,1]\n\t"
      "v_pk_fma_f32 %0, %1, %2, %0 op_sel:[1,1,0] op_sel_hi:[1,0,1] neg_lo:[1,0,0]"
      : "=&v"(o) : "v"(u), "v"(s));
  return o;
}

// ---------------------------------------------------------------------------
// Kernel A: U[k,b] = exp(-i * H_k * t_{k,b}),  H_k = 0.5*(A + A^H), A = Hr + i Hi
// 256 threads: 64 tasks (k,b) x 4 rows. Scaling (2^-4) + 8-term Taylor +
// 4 squarings (trunc error ~1e-10, invisible at fp32 / 2.1e-4 threshold).
// ---------------------------------------------------------------------------
__global__ __launch_bounds__(256) void compute_u_kernel(
    const float* __restrict__ Hre, const float* __restrict__ Him,
    const float* __restrict__ tevo, float* __restrict__ uout) {
  __shared__ float er_s[64][4][4];
  __shared__ float ei_s[64][4][4];

  const int tid  = threadIdx.x;   // 0..255
  const int task = tid >> 2;      // 0..63
  const int row  = tid & 3;      // 0..3
  const int k    = task >> 4;     // 0..3
  const int b    = task & 15;     // 0..15

  float Ar[4][4], Ai[4][4];
#pragma unroll
  for (int i = 0; i < 4; i++) {
#pragma unroll
    for (int j = 0; j < 4; j++) {
      Ar[i][j] = Hre[k * 16 + i * 4 + j];
      Ai[i][j] = Him[k * 16 + i * 4 + j];
    }
  }
  const float t = tevo[k * NB + b];
  const float ts = t * (1.0f / 16.0f);  // scale 2^-4 folded in

  // G = -i * H * ts ; H = 0.5*(A + A^H)
  float Gr[4][4], Gi[4][4];
#pragma unroll
  for (int i = 0; i < 4; i++) {
#pragma unroll
    for (int j = 0; j < 4; j++) {
      const float hr = 0.5f * (Ar[i][j] + Ar[j][i]);
      const float hi = 0.5f * (Ai[i][j] - Ai[j][i]);
      Gr[i][j] = ts * hi;
      Gi[i][j] = -ts * hr;
    }
  }

  // Taylor: E = I + sum_{m=1..8} G^m/m!   (row `row` only; full G in regs)
  float Er[4], Ei[4], Tr[4], Ti[4];
#pragma unroll
  for (int j = 0; j < 4; j++) {
    Er[j] = (j == row) ? 1.0f : 0.0f;
    Ei[j] = 0.0f;
    Tr[j] = Er[j];
    Ti[j] = 0.0f;
  }
#pragma unroll
  for (int m = 1; m <= 8; m++) {
    const float inv = 1.0f / (float)m;
    float nr[4], ni[4];
#pragma unroll
    for (int j = 0; j < 4; j++) {
      float ar = 0.0f, ai = 0.0f;
#pragma unroll
      for (int p = 0; p < 4; p++) {
        ar += Tr[p] * Gr[p][j] - Ti[p] * Gi[p][j];
        ai += Tr[p] * Gi[p][j] + Ti[p] * Gr[p][j];
      }
      nr[j] = ar * inv;
      ni[j] = ai * inv;
    }
#pragma unroll
    for (int j = 0; j < 4; j++) {
      Tr[j] = nr[j]; Ti[j] = ni[j];
      Er[j] += nr[j]; Ei[j] += ni[j];
    }
  }

  // 4 squarings via LDS (uniform trip count -> barriers are safe)
  for (int q = 0; q < 4; q++) {
    __syncthreads();
#pragma unroll
    for (int j = 0; j < 4; j++) {
      er_s[task][row][j] = Er[j];
      ei_s[task][row][j] = Ei[j];
    }
    __syncthreads();
    float nr[4], ni[4];
#pragma unroll
    for (int j = 0; j < 4; j++) {
      float ar = 0.0f, ai = 0.0f;
#pragma unroll
      for (int p = 0; p < 4; p++) {
        ar += Er[p] * er_s[task][p][j] - Ei[p] * ei_s[task][p][j];
        ai += Er[p] * ei_s[task][p][j] + Ei[p] * er_s[task][p][j];
      }
      nr[j] = ar; ni[j] = ai;
    }
#pragma unroll
    for (int j = 0; j < 4; j++) { Er[j] = nr[j]; Ei[j] = ni[j]; }
  }

  // Store U rows: layout [k][b][16 complex interleaved], row stride 36 floats
  const int ubase = (k * 16 + b) * USTRIDE;
#pragma unroll
  for (int j = 0; j < 4; j++) {
    uout[ubase + (row * 4 + j) * 2]     = Er[j];
    uout[ubase + (row * 4 + j) * 2 + 1] = Ei[j];
  }
}

// ---------------------------------------------------------------------------
// Kernel B (r22 structure, the measured optimum: 50.2 us, 2x verified):
// Block = 64 columns; wave w owns g-quadrant w (g = w*8..w*8+7), lane l owns
// column c0+l. State tile layout: [g][re x64 | im x64] (128 floats/plane,
// 16 KiB total). DMA: 16 global_load_lds width-16 instrs; instr p covers
// planes 2p,2p+1 with PER-LANE source selection -- the LDS dest is the
// required linear lane*16B, the global src is free per-lane (m104).
// Each (re,im) state read is a fused ds_read2_b32 (offset delta 64 dwords).
// Gates k=1..3 in-thread/quadrant-local; k=0 mixes quadrants via LDS reads.
// pk-FMA complex math; NT stores; 25.6 KB LDS -> 6 blocks/CU, ~50% occ.
// ---------------------------------------------------------------------------
__global__ __launch_bounds__(256, 4) void apply_gates_kernel(
    const float* __restrict__ sre, const float* __restrict__ sim,
    const float* __restrict__ u, float* __restrict__ out) {
  __shared__ __align__(16) float ul[UTOT];      // 9216 B U table
  __shared__ __align__(16) float st[32 * 128];  // 16 KiB tile [g][re64|im64]
  const int tid = threadIdx.x;
  const int w   = tid >> 6;     // wave = owned quadrant (g bits [4:3])
  const int l   = tid & 63;     // lane = column within block
  const int c0  = blockIdx.x * 64;
  const int b   = l & 15;
  const int q0  = w & 1;        // g bit 3

  // (1) DMA the state tile: 4 instrs/wave, 1 KiB each (2 planes/instr).
  //     instr p: sub = l>>4; g = 2p + (sub>>1); sub&1 ? im : re;
  //     cols (l&15)*4 .. +3 ; dest = st + p*256 floats (linear lane*16B).
#pragma unroll
  for (int t = 0; t < 4; t++) {
    const int p   = w * 4 + t;            // 0..15, wave-uniform
    const int sub = l >> 4;               // 0..3
    const int g   = 2 * p + (sub >> 1);   // 0..31
    const float* base = (sub & 1) ? sim : sre;
    const float* src  = base + (g << 19) + c0 + (l & 15) * 4;
    float* dst = st + p * 256;            // wave-uniform base, lane*16B implicit
    __builtin_amdgcn_global_load_lds(
        (const __attribute__((address_space(1))) float*)(const void*)src,
        (__attribute__((address_space(3))) float*)(void*)dst, 16, 0, 0);
  }

  // (2) stage U table cooperatively (barrier below orders it)
#pragma unroll
  for (int q = 0; q < 9; q++) ul[tid + q * 256] = u[tid + q * 256];

  __syncthreads();   // drains DMA (vmcnt) + U writes (lgkmcnt)

  // (3) own quadrant into registers: 8 paired reads (ds_read2_b32)
  float2 s[8];
#pragma unroll
  for (int m = 0; m < 8; m++) {
    const int a = (w * 8 + m) * 128 + l;
    s[m].x = st[a];
    s[m].y = st[a + 64];
  }

  float2 o[8];

  // ---- k = 3 (g bits [1:0]) : in-thread; initializes acc ----
  // o[h*4+i] = sum_j U3[i][j] * s[h*4+j]
  {
    const float* ub = &ul[(3 * 16 + b) * USTRIDE];
#pragma unroll
    for (int i = 0; i < 4; i++) {
      const float4 v0 = *(const float4*)(ub + i * 8);
      const float4 v1 = *(const float4*)(ub + i * 8 + 4);
      const float2 u0 = make_float2(v0.x, v0.y), u1 = make_float2(v0.z, v0.w);
      const float2 u2 = make_float2(v1.x, v1.y), u3 = make_float2(v1.z, v1.w);
#pragma unroll
      for (int h = 0; h < 2; h++) {
        const int om = h * 4 + i;
        o[om] = cmul(u0, s[h * 4 + 0]);
        cfma(o[om], u1, s[h * 4 + 1]);
        cfma(o[om], u2, s[h * 4 + 2]);
        cfma(o[om], u3, s[h * 4 + 3]);
      }
    }
  }

  // ---- k = 2 (g bits [2:1]) : in-thread ----
  // o[i*2+l0] += sum_j U2[i][j] * s[j*2+l0]
  {
    const float* ub = &ul[(2 * 16 + b) * USTRIDE];
#pragma unroll
    for (int i = 0; i < 4; i++) {
      const float4 v0 = *(const float4*)(ub + i * 8);
      const float4 v1 = *(const float4*)(ub + i * 8 + 4);
      const float2 u0 = make_float2(v0.x, v0.y), u1 = make_float2(v0.z, v0.w);
      const float2 u2 = make_float2(v1.x, v1.y), u3 = make_float2(v1.z, v1.w);
#pragma unroll
      for (int l0 = 0; l0 < 2; l0++) {
        const int om = i * 2 + l0;
        cfma(o[om], u0, s[l0]);
        cfma(o[om], u1, s[2 + l0]);
        cfma(o[om], u2, s[4 + l0]);
        cfma(o[om], u3, s[6 + l0]);
      }
    }
  }

  // ---- k = 1 (g bits [3:2]) + k = 0's j=w^1 term (reuses p[]) ----
  // out i = q0*2 + (m>>2); src bits[3:2]=(j3,j2): j3=q0 -> own s, j3=q0^1 ->
  // partner quadrant w^1 (p[], paired LDS reads).
  {
    float2 p[8];
    const int pq = w ^ 1;
#pragma unroll
    for (int m = 0; m < 8; m++) {
      const int a = (pq * 8 + m) * 128 + l;
      p[m].x = st[a];
      p[m].y = st[a + 64];
    }
    const float* ub1 = &ul[(1 * 16 + b) * USTRIDE];
#pragma unroll
    for (int mh = 0; mh < 2; mh++) {
      const int i = q0 * 2 + mh;
      const float* row = ub1 + i * 8;
#pragma unroll
      for (int j2 = 0; j2 < 2; j2++) {
        const float2 uo = *(const float2*)(row + (q0 * 2 + j2) * 2);
        const float2 up = *(const float2*)(row + ((q0 ^ 1) * 2 + j2) * 2);
#pragma unroll
        for (int ml = 0; ml < 4; ml++) {
          const int om = mh * 4 + ml;
          cfma(o[om], uo, s[j2 * 4 + ml]);
          cfma(o[om], up, p[j2 * 4 + ml]);
        }
      }
    }
    // k=0 term j = w^1 while p[] is live: o[m] += U0[w][w^1] * p[m]
    const float* ub0 = &ul[b * USTRIDE];
    const float2 u01 = *(const float2*)(ub0 + (w * 4 + (w ^ 1)) * 2);
#pragma unroll
    for (int m = 0; m < 8; m++) cfma(o[m], u01, p[m]);
  }

  // ---- k = 0 remaining: j = w (own regs), j = w^2, w^3 (paired LDS) ----
  {
    const float* ub0 = &ul[b * USTRIDE];
    const float2 u00 = *(const float2*)(ub0 + (w * 4 + w) * 2);
#pragma unroll
    for (int m = 0; m < 8; m++) cfma(o[m], u00, s[m]);
#pragma unroll
    for (int d = 2; d < 4; d++) {
      const int jq = w ^ d;
      const float2 uj = *(const float2*)(ub0 + (w * 4 + jq) * 2);
#pragma unroll
      for (int m = 0; m < 8; m++) {
        const int a = (jq * 8 + m) * 128 + l;
        float2 t;
        t.x = st[a];
        t.y = st[a + 64];
        cfma(o[m], uj, t);
      }
    }
  }

  // stores: 64 lanes x 4B contiguous = 256B (full lines) per instruction
#pragma unroll
  for (int m = 0; m < 8; m++) {
    const int off = c0 + l + ((w * 8 + m) << 19);
    __builtin_nontemporal_store(o[m].x, out + off);               // real
    __builtin_nontemporal_store(o[m].y, out + off + (1 << 24));   // imag
  }
}

extern "C" void kernel_launch(void* const* d_in, const int* in_sizes, int n_in,
                              void* d_out, int out_size, void* d_ws, size_t ws_size,
                              hipStream_t stream) {
  const float* Hre  = (const float*)d_in[0];
  const float* Him  = (const float*)d_in[1];
  const float* tevo = (const float*)d_in[2];
  const float* sre  = (const float*)d_in[3];
  const float* sim  = (const float*)d_in[4];
  float* out = (float*)d_out;
  float* uws = (float*)d_ws;  // UTOT floats = 9216 B

  compute_u_kernel<<<1, 256, 0, stream>>>(Hre, Him, tevo, uws);
  apply_gates_kernel<<<NCOL / 64, 256, 0, stream>>>(sre, sim, uws, out);
}